// Round 5
// baseline (1387.758 us; speedup 1.0000x reference)
//
#include <hip/hip_runtime.h>

#define NN 100000
#define EE 1600000
#define FF 128
#define LL 4
#define GG 512
#define OUTC 10
#define EPSF 1e-5f
#define NSCB ((NN + 255) / 256)   // 391 scan blocks

// k_agg geometry: each wave owns NPW contiguous nodes => contiguous CSR edge range
#define NPW 16
#define AGG_WAVES ((NN + NPW - 1) / NPW)
#define AGG_BLOCKS ((AGG_WAVES + 3) / 4)

typedef __attribute__((ext_vector_type(8))) short short8;
typedef __attribute__((ext_vector_type(4))) float f32x4;

__device__ inline unsigned bf16rne(float f) {
  unsigned u = __float_as_uint(f);
  return (u + 0x7fffu + ((u >> 16) & 1u)) >> 16;
}
__device__ inline unsigned packbf(float lo, float hi) {
  return bf16rne(lo) | (bf16rne(hi) << 16);
}
__device__ inline float bflo(unsigned u) { return __uint_as_float(u << 16); }
__device__ inline float bfhi(unsigned u) { return __uint_as_float(u & 0xffff0000u); }

// ---------- graph setup ----------

__global__ __launch_bounds__(256) void k_deg(const int* __restrict__ col, int* __restrict__ deg) {
  int e = blockIdx.x * 256 + threadIdx.x;
  if (e < EE) atomicAdd(&deg[col[e]], 1);
}

// per-block degree sums (391 blocks x 256) + dinv (fused elementwise)
__global__ __launch_bounds__(256) void k_bsum(const int* __restrict__ deg,
                                              int* __restrict__ bsum,
                                              float* __restrict__ dinv) {
  int i = blockIdx.x * 256 + threadIdx.x;
  int v = (i < NN) ? deg[i] : 0;
  if (i < NN) dinv[i] = v > 0 ? rsqrtf((float)v) : 0.0f;
#pragma unroll
  for (int off = 32; off > 0; off >>= 1) v += __shfl_down(v, off, 64);
  __shared__ int ws[4];
  if ((threadIdx.x & 63) == 0) ws[threadIdx.x >> 6] = v;
  __syncthreads();
  if (threadIdx.x == 0) bsum[blockIdx.x] = ws[0] + ws[1] + ws[2] + ws[3];
}

// each block: scan all block sums in LDS (redundant), local scan of its 256 degs,
// write exclusive rowptr. rowptr[NN] = EE (constant).
__global__ __launch_bounds__(256) void k_rowptr(const int* __restrict__ deg,
                                                const int* __restrict__ bsum,
                                                int* __restrict__ rowptr) {
  __shared__ int sb[512];
  __shared__ int sd[256];
  const int t = threadIdx.x;
  sb[t]       = (t < NSCB) ? bsum[t] : 0;
  sb[t + 256] = (t + 256 < NSCB) ? bsum[t + 256] : 0;
  __syncthreads();
#pragma unroll
  for (int off = 1; off < 512; off <<= 1) {
    int v0 = (t >= off) ? sb[t - off] : 0;
    int v1 = sb[t + 256 - off];
    __syncthreads();
    sb[t] += v0;
    sb[t + 256] += v1;
    __syncthreads();
  }
  const int bpre = (blockIdx.x == 0) ? 0 : sb[blockIdx.x - 1];
  const int i = blockIdx.x * 256 + t;
  const int d = (i < NN) ? deg[i] : 0;
  sd[t] = d;
  __syncthreads();
#pragma unroll
  for (int off = 1; off < 256; off <<= 1) {
    int v = (t >= off) ? sd[t - off] : 0;
    __syncthreads();
    sd[t] += v;
    __syncthreads();
  }
  if (i < NN) rowptr[i] = bpre + sd[t] - d;
  if (blockIdx.x == 0 && t == 0) rowptr[NN] = EE;
}

// build CSR: one interleaved (src, weight) int2 store per edge
__global__ __launch_bounds__(256) void k_fill(const int* __restrict__ ei,
                                              const int* __restrict__ rowptr,
                                              int* __restrict__ cnt,
                                              const float* __restrict__ dinv,
                                              int2* __restrict__ ecw) {
  int e = blockIdx.x * 256 + threadIdx.x;
  if (e >= EE) return;
  int r = ei[e];
  int cl = ei[EE + e];
  int slot = rowptr[cl] + atomicAdd(&cnt[cl], 1);
  ecw[slot] = make_int2(r, __float_as_int(dinv[r] * dinv[cl]));
}

// ---------- bf16 conversions ----------

// x[N,128] fp32 -> Ab packed bf16 pairs; fused: gstart bounds from sorted batch
__global__ __launch_bounds__(256) void k_cvt(const float* __restrict__ x,
                                             const int* __restrict__ batch,
                                             unsigned* __restrict__ Ab,
                                             int* __restrict__ gstart) {
  int i = blockIdx.x * 256 + threadIdx.x;
  if (i < NN * 64) {
    float2 v = *(const float2*)(x + (size_t)i * 2);
    Ab[i] = packbf(v.x, v.y);
  }
  if (i < NN) {
    int b = batch[i];
    if (i == 0) {
      for (int g = 0; g <= b; ++g) gstart[g] = 0;
    } else {
      int bp = batch[i - 1];
      for (int g = bp + 1; g <= b; ++g) gstart[g] = i;
    }
    if (i == NN - 1) {
      for (int g = b + 1; g <= GG; ++g) gstart[g] = NN;
    }
  }
}

// W[128,128] fp32 -> MFMA B-fragments, hi/lo bf16 split (layer-0, no scale).
// frag index: ((kc*8 + ct)*2 + which), 64 lanes * 16B.
__global__ __launch_bounds__(256) void k_wcvt(const float* __restrict__ W,
                                              uint4* __restrict__ Wf) {
  int tid = blockIdx.x * 256 + threadIdx.x;   // 0..4095
  int lane = tid & 63;
  int which = (tid >> 6) & 1;
  int ct = (tid >> 7) & 7;
  int kc = tid >> 10;
  int n = ct * 16 + (lane & 15);
  int k0 = kc * 32 + (lane >> 4) * 8;
  unsigned h[8];
#pragma unroll
  for (int j = 0; j < 8; ++j) {
    float w = W[(k0 + j) * 128 + n];
    unsigned hb = bf16rne(w);
    if (which == 0) {
      h[j] = hb;
    } else {
      float hf = __uint_as_float(hb << 16);
      h[j] = bf16rne(w - hf);
    }
  }
  uint4 o;
  o.x = h[0] | (h[1] << 16);
  o.y = h[2] | (h[3] << 16);
  o.z = h[4] | (h[5] << 16);
  o.w = h[6] | (h[7] << 16);
  Wf[tid] = o;
}

// ---------- per-layer GEMM via MFMA: Bb[N,128](packed bf16) = Ab @ (Whi+Wlo) ----------
// 32 rows per wave (2 row-fragments), 128 rows per block: halves per-row Wf
// re-streaming from L2 and per-row instruction overhead vs 16 rows/wave.
__global__ __launch_bounds__(256) void k_mm(const unsigned* __restrict__ Ab,
                                            const uint4* __restrict__ Wf,
                                            unsigned* __restrict__ Bb) {
  const int lane = threadIdx.x & 63;
  const int w = threadIdx.x >> 6;
  const int quad = lane >> 4;
  const int m = lane & 15;
  const int rowbase = blockIdx.x * 128 + w * 32;
  const int arow0 = min(rowbase + m, NN - 1);
  const int arow1 = min(rowbase + 16 + m, NN - 1);
  const uint4* A4 = (const uint4*)Ab;
  f32x4 acc[2][8];
#pragma unroll
  for (int rf = 0; rf < 2; ++rf)
#pragma unroll
    for (int ct = 0; ct < 8; ++ct) acc[rf][ct] = (f32x4){0.f, 0.f, 0.f, 0.f};
#pragma unroll
  for (int kc = 0; kc < 4; ++kc) {
    uint4 av0 = A4[arow0 * 16 + kc * 4 + quad];
    uint4 av1 = A4[arow1 * 16 + kc * 4 + quad];
    short8 af0 = *(short8*)&av0;
    short8 af1 = *(short8*)&av1;
#pragma unroll
    for (int ct = 0; ct < 8; ++ct) {
      uint4 bh = Wf[((kc * 8 + ct) * 2 + 0) * 64 + lane];
      uint4 bl = Wf[((kc * 8 + ct) * 2 + 1) * 64 + lane];
      short8 bhf = *(short8*)&bh;
      short8 blf = *(short8*)&bl;
      acc[0][ct] = __builtin_amdgcn_mfma_f32_16x16x32_bf16(af0, bhf, acc[0][ct], 0, 0, 0);
      acc[0][ct] = __builtin_amdgcn_mfma_f32_16x16x32_bf16(af0, blf, acc[0][ct], 0, 0, 0);
      acc[1][ct] = __builtin_amdgcn_mfma_f32_16x16x32_bf16(af1, bhf, acc[1][ct], 0, 0, 0);
      acc[1][ct] = __builtin_amdgcn_mfma_f32_16x16x32_bf16(af1, blf, acc[1][ct], 0, 0, 0);
    }
  }
#pragma unroll
  for (int rf = 0; rf < 2; ++rf) {
#pragma unroll
    for (int ct = 0; ct < 8; ++ct) {
#pragma unroll
      for (int r = 0; r < 4; ++r) {
        float v = acc[rf][ct][r];
        float vo = __shfl_xor(v, 1);
        int row = rowbase + rf * 16 + quad * 4 + r;
        if ((lane & 1) == 0 && row < NN) {
          Bb[row * 64 + ct * 8 + (m >> 1)] = packbf(v, vo);
        }
      }
    }
  }
}

// ---------- aggregation (+ fused per-layer epilogue in last-finishing block) ----------
// Ar[n] = packbf(relu(sum_e w*B[src] + (sum_e w)*base + bias)), BN partial sums,
// and per-graph pooled raw sums (pooling of BN output is affine -> applied in k_z1).
// Each wave owns NPW contiguous nodes => one contiguous CSR edge range (round-1
// measured-best inner loop: single ew buffer, 16 gathers in flight per group).
// Last block (device-scope ticket): computes BN affine -> bnsc, and (if Wnext)
// next layer's scaled Wf fragments + base vector. Replaces the k_post dispatch.
__global__ __launch_bounds__(256) void k_agg(const unsigned* __restrict__ Bb,
                                             const int* __restrict__ rowptr,
                                             const int2* __restrict__ ecw,
                                             const float* __restrict__ bias,
                                             const float* __restrict__ base,
                                             const int* __restrict__ batch,
                                             unsigned* __restrict__ Ar,
                                             float* __restrict__ bnbuf,
                                             float* __restrict__ pooledt,
                                             const float* __restrict__ gamma,
                                             const float* __restrict__ beta,
                                             float* __restrict__ bnsc,
                                             const float* __restrict__ Wnext,
                                             uint4* __restrict__ Wf,
                                             float* __restrict__ baseo,
                                             unsigned* __restrict__ ctr) {
  const int lane = threadIdx.x & 63;
  const int wave = threadIdx.x >> 6;
  const int c = lane * 2;
  const int gwave = blockIdx.x * 4 + wave;
  const int n0 = gwave * NPW;
  const float2 bv = *(const float2*)(bias + c);
  const float2 basev = *(const float2*)(base + c);
  float s0 = 0.f, s1 = 0.f, q0 = 0.f, q1 = 0.f;
  __shared__ int srp[4][NPW + 1];
  __shared__ int2 sstage[4][64];
  if (n0 < NN) {
    const int nn = min(NPW, NN - n0);
    if (lane <= nn) srp[wave][lane] = rowptr[n0 + lane];
    int bsp = (lane < nn) ? batch[n0 + lane] : 0;
    float ax0 = 0.f, ax1 = 0.f, ay0 = 0.f, ay1 = 0.f, sw = 0.f;
    float px = 0.f, py = 0.f;
    int gprev = -1;
    auto finalize = [&](int node) {
      float rx = fmaxf(fmaf(sw, basev.x, ax0 + ax1) + bv.x, 0.f);
      float ry = fmaxf(fmaf(sw, basev.y, ay0 + ay1) + bv.y, 0.f);
      Ar[(size_t)(n0 + node) * 64 + lane] = packbf(rx, ry);
      s0 += rx; s1 += ry;
      q0 = fmaf(rx, rx, q0); q1 = fmaf(ry, ry, q1);
      int g = __shfl(bsp, node);
      if (g != gprev) {
        if (gprev >= 0) {
          atomicAdd(&pooledt[(size_t)gprev * 512 + c], px);
          atomicAdd(&pooledt[(size_t)gprev * 512 + c + 1], py);
        }
        gprev = g; px = 0.f; py = 0.f;
      }
      px += rx; py += ry;
      ax0 = 0.f; ax1 = 0.f; ay0 = 0.f; ay1 = 0.f; sw = 0.f;
    };
    const int beg = __builtin_amdgcn_readfirstlane(srp[wave][0]);
    const int endall = __builtin_amdgcn_readfirstlane(srp[wave][nn]);
    int cn = 0;
    // leading (and possibly all) empty nodes
    while (cn < nn && __builtin_amdgcn_readfirstlane(srp[wave][cn + 1]) == beg) {
      finalize(cn);
      ++cn;
    }
    int nend = (cn < nn) ? __builtin_amdgcn_readfirstlane(srp[wave][cn + 1]) : 0x7fffffff;
    int2 stage = (beg + lane < endall) ? ecw[beg + lane] : make_int2(0, 0);
    for (int base_e = beg; base_e < endall; base_e += 64) {
      sstage[wave][lane] = stage;     // current chunk -> LDS (same-wave, in-order)
      const int nb = base_e + 64;
      if (nb < endall) {              // prefetch next chunk off critical path
        stage = (nb + lane < endall) ? ecw[nb + lane] : make_int2(0, 0);
      }
#pragma unroll
      for (int g = 0; g < 4; ++g) {
        if (base_e + g * 16 < endall) {   // wave-uniform (SGPR) branch
          int2 ew[16]; unsigned us[16];
#pragma unroll
          for (int j = 0; j < 16; ++j) ew[j] = sstage[wave][g * 16 + j];  // broadcast
#pragma unroll
          for (int j = 0; j < 16; ++j) {
            const int sj = __builtin_amdgcn_readfirstlane(ew[j].x);       // SGPR base
            us[j] = Bb[((size_t)(unsigned)sj << 6) + (unsigned)lane];
          }
#pragma unroll
          for (int j = 0; j < 16; ++j) {
            const float wj = __int_as_float(ew[j].y);   // 0 for padding lanes
            sw += wj;
            if (j & 1) {
              ax1 = fmaf(wj, bflo(us[j]), ax1);
              ay1 = fmaf(wj, bfhi(us[j]), ay1);
            } else {
              ax0 = fmaf(wj, bflo(us[j]), ax0);
              ay0 = fmaf(wj, bfhi(us[j]), ay0);
            }
            const int e1 = base_e + g * 16 + j + 1;     // scalar
            if (e1 == nend) {                           // node boundary (SGPR cmp)
              finalize(cn);
              ++cn;
              nend = (cn < nn) ? __builtin_amdgcn_readfirstlane(srp[wave][cn + 1]) : 0x7fffffff;
              while (cn < nn && nend == e1) {           // empty nodes inside span
                finalize(cn);
                ++cn;
                nend = (cn < nn) ? __builtin_amdgcn_readfirstlane(srp[wave][cn + 1]) : 0x7fffffff;
              }
            }
          }
        }
      }
    }
    if (gprev >= 0) {
      atomicAdd(&pooledt[(size_t)gprev * 512 + c], px);
      atomicAdd(&pooledt[(size_t)gprev * 512 + c + 1], py);
    }
  }
  __shared__ float sred[4][256];
  sred[wave][c] = s0;
  sred[wave][c + 1] = s1;
  sred[wave][128 + c] = q0;
  sred[wave][128 + c + 1] = q1;
  __syncthreads();
  const int t = threadIdx.x;
  float tot = sred[0][t] + sred[1][t] + sred[2][t] + sred[3][t];
  atomicAdd(&bnbuf[t], tot);

  // ---- last-block fused epilogue (replaces k_post dispatch) ----
  __threadfence();                     // release: bnbuf adds visible before ticket
  __syncthreads();
  __shared__ int lastf;
  if (t == 0) lastf = (atomicAdd(ctr, 1u) == (unsigned)(gridDim.x - 1));
  __syncthreads();
  if (!lastf) return;
  __threadfence();                     // acquire: see all blocks' bnbuf adds
  __shared__ float ssc[256];
  if (t < 128) {
    float mu = bnbuf[t] * (1.0f / NN);
    float var = bnbuf[128 + t] * (1.0f / NN) - mu * mu;
    float inv = rsqrtf(var + EPSF);
    float sc = gamma[t] * inv;
    float sh = beta[t] - mu * sc;
    ssc[t] = sc;
    ssc[128 + t] = sh;
    bnsc[t] = sc;
    bnsc[128 + t] = sh;
  }
  __syncthreads();
  if (!Wnext) return;                  // last layer: stats only
#pragma unroll
  for (int i = 0; i < 16; ++i) {       // 4096 fragment words, 16 per thread
    int tid = t + i * 256;
    int lane2 = tid & 63;
    int which = (tid >> 6) & 1;
    int ct = (tid >> 7) & 7;
    int kc = tid >> 10;
    int n = ct * 16 + (lane2 & 15);
    int k0 = kc * 32 + (lane2 >> 4) * 8;
    unsigned h[8];
#pragma unroll
    for (int j = 0; j < 8; ++j) {
      float w = Wnext[(k0 + j) * 128 + n] * ssc[k0 + j];
      unsigned hb = bf16rne(w);
      if (which == 0) {
        h[j] = hb;
      } else {
        float hf = __uint_as_float(hb << 16);
        h[j] = bf16rne(w - hf);
      }
    }
    uint4 o;
    o.x = h[0] | (h[1] << 16);
    o.y = h[2] | (h[3] << 16);
    o.z = h[4] | (h[5] << 16);
    o.w = h[6] | (h[7] << 16);
    Wf[tid] = o;
  }
  if (t < 128) {
    float acc = 0.f;
    for (int k = 0; k < 128; ++k) acc = fmaf(ssc[128 + k], Wnext[k * 128 + t], acc);
    baseo[t] = acc;
  }
}

// ---------- head ----------

// z1 = (affine-pooled) @ W1 + b1 where pooled_gc = sc_c*S_gc + cnt_g*sh_c
// 4 graphs per block: W1 re-read drops 4x.
__global__ __launch_bounds__(128) void k_z1(const float* __restrict__ S,
                                            const float* __restrict__ bnscL,
                                            const int* __restrict__ gstart,
                                            const float* __restrict__ W1,
                                            const float* __restrict__ b1,
                                            float* __restrict__ z1) {
  __shared__ float sp[4][512];
  const int g0 = blockIdx.x * 4;
  const int c = threadIdx.x;
#pragma unroll
  for (int q = 0; q < 4; ++q) {
    const int g = g0 + q;
    const float cntg = (float)(gstart[g + 1] - gstart[g]);
    for (int i = c; i < 512; i += 128) {
      int tt = i >> 7, ch = i & 127;
      sp[q][i] = fmaf(bnscL[tt * 256 + ch], S[(size_t)g * 512 + i],
                      cntg * bnscL[tt * 256 + 128 + ch]);
    }
  }
  __syncthreads();
  float a0 = b1[c], a1 = a0, a2 = a0, a3 = a0;
  for (int j = 0; j < 512; ++j) {
    float w = W1[j * 128 + c];
    a0 = fmaf(sp[0][j], w, a0);
    a1 = fmaf(sp[1][j], w, a1);
    a2 = fmaf(sp[2][j], w, a2);
    a3 = fmaf(sp[3][j], w, a3);
  }
  z1[(size_t)(g0 + 0) * 128 + c] = a0;
  z1[(size_t)(g0 + 1) * 128 + c] = a1;
  z1[(size_t)(g0 + 2) * 128 + c] = a2;
  z1[(size_t)(g0 + 3) * 128 + c] = a3;
}

// 1024 threads: 8 g-strided partial passes (coalesced in c) + LDS reduce
__global__ __launch_bounds__(1024) void k_zstat(const float* __restrict__ z1,
                                                const float* __restrict__ g1,
                                                const float* __restrict__ bt1,
                                                float* __restrict__ zsc) {
  const int t = threadIdx.x;
  const int c = t & 127;
  const int gr = t >> 7;   // 0..7
  float s = 0.f, q = 0.f;
  for (int g = gr; g < GG; g += 8) {
    float v = z1[(size_t)g * 128 + c];
    s += v;
    q = fmaf(v, v, q);
  }
  __shared__ float ss[8][128];
  __shared__ float sq[8][128];
  ss[gr][c] = s;
  sq[gr][c] = q;
  __syncthreads();
  if (t < 128) {
    float st = 0.f, qt = 0.f;
#pragma unroll
    for (int i = 0; i < 8; ++i) { st += ss[i][c]; qt += sq[i][c]; }
    float mu = st * (1.0f / GG);
    float var = qt * (1.0f / GG) - mu * mu;
    float inv = rsqrtf(var + EPSF);
    float sc = g1[c] * inv;
    zsc[c] = sc;
    zsc[128 + c] = bt1[c] - mu * sc;
  }
}

__global__ __launch_bounds__(128) void k_out(const float* __restrict__ z1,
                                             const float* __restrict__ zsc,
                                             const float* __restrict__ W2,
                                             const float* __restrict__ b2,
                                             float* __restrict__ out) {
  __shared__ float zr[128];
  const int g = blockIdx.x;
  const int c = threadIdx.x;
  zr[c] = fmaxf(fmaf(z1[(size_t)g * 128 + c], zsc[c], zsc[128 + c]), 0.f);
  __syncthreads();
  if (c < OUTC) {
    float acc = b2[c];
    for (int k = 0; k < 128; ++k) acc = fmaf(zr[k], W2[k * OUTC + c], acc);
    out[(size_t)g * OUTC + c] = acc;
  }
}

// ---------- launch ----------

extern "C" void kernel_launch(void* const* d_in, const int* in_sizes, int n_in,
                              void* d_out, int out_size, void* d_ws, size_t ws_size,
                              hipStream_t stream) {
  const float* x      = (const float*)d_in[0];
  const int*   ei     = (const int*)d_in[1];
  const int*   batch  = (const int*)d_in[2];
  const float* Ws     = (const float*)d_in[3];
  const float* bs     = (const float*)d_in[4];
  const float* gammas = (const float*)d_in[5];
  const float* betas  = (const float*)d_in[6];
  const float* W1     = (const float*)d_in[7];
  const float* b1     = (const float*)d_in[8];
  const float* g1     = (const float*)d_in[9];
  const float* bt1    = (const float*)d_in[10];
  const float* W2     = (const float*)d_in[11];
  const float* b2     = (const float*)d_in[12];
  float* out = (float*)d_out;

  char* ws = (char*)d_ws;
  size_t off = 0;
  auto alloc = [&](size_t bytes) -> void* {
    void* p = ws + off;
    off = (off + bytes + 255) & ~(size_t)255;
    return p;
  };
  // zero-initialized region (single memset)
  int*   deg    = (int*)alloc((size_t)NN * 4);
  int*   cnt    = (int*)alloc((size_t)NN * 4);
  float* bnbuf  = (float*)alloc((size_t)LL * 256 * 4);
  float* pooled = (float*)alloc((size_t)GG * 512 * 4);
  float* zbase  = (float*)alloc(128 * 4);            // zeros: layer-0 base term
  unsigned* ctr = (unsigned*)alloc((size_t)LL * 4);  // per-layer last-block tickets
  size_t zero_bytes = off;
  // rest
  unsigned* Ar     = (unsigned*)alloc((size_t)NN * 64 * 4); // packed bf16 relu output
  unsigned* Ab     = (unsigned*)alloc((size_t)NN * 64 * 4); // packed bf16 layer-0 GEMM input
  unsigned* Bb     = (unsigned*)alloc((size_t)NN * 64 * 4); // packed bf16 H@W (gather src)
  int2*     ecw    = (int2*)alloc((size_t)EE * 8);
  float*    dinv   = (float*)alloc((size_t)NN * 4);
  int*      rowptr = (int*)alloc((size_t)(NN + 1) * 4);
  int*      bsum   = (int*)alloc((size_t)NSCB * 4);
  int*      gstart = (int*)alloc((size_t)(GG + 1) * 4);
  uint4*    Wf     = (uint4*)alloc((size_t)4096 * 16);      // MFMA W fragments (hi/lo), one layer
  float*    z1     = (float*)alloc((size_t)GG * FF * 4);
  float*    bnscL  = (float*)alloc((size_t)LL * 256 * 4);   // per-layer BN (sc, sh)
  float*    basebf = (float*)alloc(128 * 4);                // sh @ W_{t+1}
  float*    zsc    = (float*)alloc(256 * 4);
  (void)ws_size; (void)in_sizes; (void)n_in; (void)out_size;

  hipMemsetAsync(d_ws, 0, zero_bytes, stream);

  k_deg<<<(EE + 255) / 256, 256, 0, stream>>>(ei + EE, deg);
  k_bsum<<<NSCB, 256, 0, stream>>>(deg, bsum, dinv);
  k_rowptr<<<NSCB, 256, 0, stream>>>(deg, bsum, rowptr);
  k_fill<<<(EE + 255) / 256, 256, 0, stream>>>(ei, rowptr, cnt, dinv, ecw);
  k_cvt<<<(NN * 64 + 255) / 256, 256, 0, stream>>>(x, batch, Ab, gstart);
  k_wcvt<<<16, 256, 0, stream>>>(Ws, Wf);

  for (int t = 0; t < LL; ++t) {
    k_mm<<<(NN + 127) / 128, 256, 0, stream>>>(t == 0 ? Ab : Ar, Wf, Bb);
    k_agg<<<AGG_BLOCKS, 256, 0, stream>>>(
        Bb, rowptr, ecw, bs + t * FF, t == 0 ? zbase : basebf, batch,
        Ar, bnbuf + t * 256, pooled + t * FF,
        gammas + t * FF, betas + t * FF, bnscL + t * 256,
        t < LL - 1 ? Ws + (size_t)(t + 1) * 16384 : nullptr, Wf, basebf, ctr + t);
  }

  k_z1<<<GG / 4, 128, 0, stream>>>(pooled, bnscL, gstart, W1, b1, z1);
  k_zstat<<<1, 1024, 0, stream>>>(z1, g1, bt1, zsc);
  k_out<<<GG, 128, 0, stream>>>(z1, zsc, W2, b2, out);
}

// Round 6
// 814.862 us; speedup vs baseline: 1.7031x; 1.7031x over previous
//
#include <hip/hip_runtime.h>

#define NN 100000
#define EE 1600000
#define FF 128
#define LL 4
#define GG 512
#define OUTC 10
#define EPSF 1e-5f
#define NSCB ((NN + 255) / 256)   // 391 scan blocks

// k_agg geometry: each wave owns NPW contiguous nodes => contiguous CSR edge range
#define NPW 16
#define AGG_WAVES ((NN + NPW - 1) / NPW)
#define AGG_BLOCKS ((AGG_WAVES + 3) / 4)

typedef __attribute__((ext_vector_type(8))) short short8;
typedef __attribute__((ext_vector_type(4))) float f32x4;

__device__ inline unsigned bf16rne(float f) {
  unsigned u = __float_as_uint(f);
  return (u + 0x7fffu + ((u >> 16) & 1u)) >> 16;
}
__device__ inline unsigned packbf(float lo, float hi) {
  return bf16rne(lo) | (bf16rne(hi) << 16);
}
__device__ inline float bflo(unsigned u) { return __uint_as_float(u << 16); }
__device__ inline float bfhi(unsigned u) { return __uint_as_float(u & 0xffff0000u); }

// ---------- graph setup ----------

__global__ __launch_bounds__(256) void k_deg(const int* __restrict__ col, int* __restrict__ deg) {
  int e = blockIdx.x * 256 + threadIdx.x;
  if (e < EE) atomicAdd(&deg[col[e]], 1);
}

// per-block degree sums (391 blocks x 256) + dinv (fused elementwise)
__global__ __launch_bounds__(256) void k_bsum(const int* __restrict__ deg,
                                              int* __restrict__ bsum,
                                              float* __restrict__ dinv) {
  int i = blockIdx.x * 256 + threadIdx.x;
  int v = (i < NN) ? deg[i] : 0;
  if (i < NN) dinv[i] = v > 0 ? rsqrtf((float)v) : 0.0f;
#pragma unroll
  for (int off = 32; off > 0; off >>= 1) v += __shfl_down(v, off, 64);
  __shared__ int ws[4];
  if ((threadIdx.x & 63) == 0) ws[threadIdx.x >> 6] = v;
  __syncthreads();
  if (threadIdx.x == 0) bsum[blockIdx.x] = ws[0] + ws[1] + ws[2] + ws[3];
}

// each block: scan all block sums in LDS (redundant), local scan of its 256 degs,
// write exclusive rowptr. rowptr[NN] = EE (constant).
__global__ __launch_bounds__(256) void k_rowptr(const int* __restrict__ deg,
                                                const int* __restrict__ bsum,
                                                int* __restrict__ rowptr) {
  __shared__ int sb[512];
  __shared__ int sd[256];
  const int t = threadIdx.x;
  sb[t]       = (t < NSCB) ? bsum[t] : 0;
  sb[t + 256] = (t + 256 < NSCB) ? bsum[t + 256] : 0;
  __syncthreads();
#pragma unroll
  for (int off = 1; off < 512; off <<= 1) {
    int v0 = (t >= off) ? sb[t - off] : 0;
    int v1 = sb[t + 256 - off];
    __syncthreads();
    sb[t] += v0;
    sb[t + 256] += v1;
    __syncthreads();
  }
  const int bpre = (blockIdx.x == 0) ? 0 : sb[blockIdx.x - 1];
  const int i = blockIdx.x * 256 + t;
  const int d = (i < NN) ? deg[i] : 0;
  sd[t] = d;
  __syncthreads();
#pragma unroll
  for (int off = 1; off < 256; off <<= 1) {
    int v = (t >= off) ? sd[t - off] : 0;
    __syncthreads();
    sd[t] += v;
    __syncthreads();
  }
  if (i < NN) rowptr[i] = bpre + sd[t] - d;
  if (blockIdx.x == 0 && t == 0) rowptr[NN] = EE;
}

// build CSR: one interleaved (src, weight) int2 store per edge
__global__ __launch_bounds__(256) void k_fill(const int* __restrict__ ei,
                                              const int* __restrict__ rowptr,
                                              int* __restrict__ cnt,
                                              const float* __restrict__ dinv,
                                              int2* __restrict__ ecw) {
  int e = blockIdx.x * 256 + threadIdx.x;
  if (e >= EE) return;
  int r = ei[e];
  int cl = ei[EE + e];
  int slot = rowptr[cl] + atomicAdd(&cnt[cl], 1);
  ecw[slot] = make_int2(r, __float_as_int(dinv[r] * dinv[cl]));
}

// ---------- bf16 conversions ----------

// x[N,128] fp32 -> Ab packed bf16 pairs; fused: gstart bounds from sorted batch
__global__ __launch_bounds__(256) void k_cvt(const float* __restrict__ x,
                                             const int* __restrict__ batch,
                                             unsigned* __restrict__ Ab,
                                             int* __restrict__ gstart) {
  int i = blockIdx.x * 256 + threadIdx.x;
  if (i < NN * 64) {
    float2 v = *(const float2*)(x + (size_t)i * 2);
    Ab[i] = packbf(v.x, v.y);
  }
  if (i < NN) {
    int b = batch[i];
    if (i == 0) {
      for (int g = 0; g <= b; ++g) gstart[g] = 0;
    } else {
      int bp = batch[i - 1];
      for (int g = bp + 1; g <= b; ++g) gstart[g] = i;
    }
    if (i == NN - 1) {
      for (int g = b + 1; g <= GG; ++g) gstart[g] = NN;
    }
  }
}

// W[128,128] fp32 -> MFMA B-fragments, hi/lo bf16 split (layer-0, no scale).
// frag index: ((kc*8 + ct)*2 + which), 64 lanes * 16B.
__global__ __launch_bounds__(256) void k_wcvt(const float* __restrict__ W,
                                              uint4* __restrict__ Wf) {
  int tid = blockIdx.x * 256 + threadIdx.x;   // 0..4095
  int lane = tid & 63;
  int which = (tid >> 6) & 1;
  int ct = (tid >> 7) & 7;
  int kc = tid >> 10;
  int n = ct * 16 + (lane & 15);
  int k0 = kc * 32 + (lane >> 4) * 8;
  unsigned h[8];
#pragma unroll
  for (int j = 0; j < 8; ++j) {
    float w = W[(k0 + j) * 128 + n];
    unsigned hb = bf16rne(w);
    if (which == 0) {
      h[j] = hb;
    } else {
      float hf = __uint_as_float(hb << 16);
      h[j] = bf16rne(w - hf);
    }
  }
  uint4 o;
  o.x = h[0] | (h[1] << 16);
  o.y = h[2] | (h[3] << 16);
  o.z = h[4] | (h[5] << 16);
  o.w = h[6] | (h[7] << 16);
  Wf[tid] = o;
}

// Fused per-layer epilogue (separate dispatch — fusing this into k_agg via
// threadfence+ticket cost 2.6x on k_agg, round 5): every block computes BN
// affine (sc, sh) from bnbuf (redundant, 512 B); block 0 stores it to bnsc.
// If gridDim>1 (not last layer): blocks 0..15 emit next layer's scaled W
// fragments, block 16 computes base[c] = sum_k sh[k]*Wnext[k,c].
__global__ __launch_bounds__(256) void k_post(const float* __restrict__ bnbuf,
                                              const float* __restrict__ gamma,
                                              const float* __restrict__ beta,
                                              float* __restrict__ bnsc,
                                              const float* __restrict__ Wnext,
                                              uint4* __restrict__ Wf,
                                              float* __restrict__ baseo) {
  __shared__ float ssc[256];
  const int t = threadIdx.x;
  if (t < 128) {
    float mu = bnbuf[t] * (1.0f / NN);
    float var = bnbuf[128 + t] * (1.0f / NN) - mu * mu;
    float inv = rsqrtf(var + EPSF);
    float sc = gamma[t] * inv;
    float sh = beta[t] - mu * sc;
    ssc[t] = sc;
    ssc[128 + t] = sh;
    if (blockIdx.x == 0) {
      bnsc[t] = sc;
      bnsc[128 + t] = sh;
    }
  }
  __syncthreads();
  if (gridDim.x == 1) return;   // last layer: stats only
  if (blockIdx.x < 16) {
    int tid = blockIdx.x * 256 + t;
    int lane = tid & 63;
    int which = (tid >> 6) & 1;
    int ct = (tid >> 7) & 7;
    int kc = tid >> 10;
    int n = ct * 16 + (lane & 15);
    int k0 = kc * 32 + (lane >> 4) * 8;
    unsigned h[8];
#pragma unroll
    for (int j = 0; j < 8; ++j) {
      float w = Wnext[(k0 + j) * 128 + n] * ssc[k0 + j];
      unsigned hb = bf16rne(w);
      if (which == 0) {
        h[j] = hb;
      } else {
        float hf = __uint_as_float(hb << 16);
        h[j] = bf16rne(w - hf);
      }
    }
    uint4 o;
    o.x = h[0] | (h[1] << 16);
    o.y = h[2] | (h[3] << 16);
    o.z = h[4] | (h[5] << 16);
    o.w = h[6] | (h[7] << 16);
    Wf[tid] = o;
  } else if (t < 128) {
    float acc = 0.f;
    for (int k = 0; k < 128; ++k) acc = fmaf(ssc[128 + k], Wnext[k * 128 + t], acc);
    baseo[t] = acc;
  }
}

// ---------- per-layer GEMM via MFMA: Bb[N,128](packed bf16) = Ab @ (Whi+Wlo) ----------
// 32 rows per wave (2 row-fragments), 128 rows per block: halves per-row Wf
// re-streaming from L2 and per-row instruction overhead vs 16 rows/wave.
__global__ __launch_bounds__(256) void k_mm(const unsigned* __restrict__ Ab,
                                            const uint4* __restrict__ Wf,
                                            unsigned* __restrict__ Bb) {
  const int lane = threadIdx.x & 63;
  const int w = threadIdx.x >> 6;
  const int quad = lane >> 4;
  const int m = lane & 15;
  const int rowbase = blockIdx.x * 128 + w * 32;
  const int arow0 = min(rowbase + m, NN - 1);
  const int arow1 = min(rowbase + 16 + m, NN - 1);
  const uint4* A4 = (const uint4*)Ab;
  f32x4 acc[2][8];
#pragma unroll
  for (int rf = 0; rf < 2; ++rf)
#pragma unroll
    for (int ct = 0; ct < 8; ++ct) acc[rf][ct] = (f32x4){0.f, 0.f, 0.f, 0.f};
#pragma unroll
  for (int kc = 0; kc < 4; ++kc) {
    uint4 av0 = A4[arow0 * 16 + kc * 4 + quad];
    uint4 av1 = A4[arow1 * 16 + kc * 4 + quad];
    short8 af0 = *(short8*)&av0;
    short8 af1 = *(short8*)&av1;
#pragma unroll
    for (int ct = 0; ct < 8; ++ct) {
      uint4 bh = Wf[((kc * 8 + ct) * 2 + 0) * 64 + lane];
      uint4 bl = Wf[((kc * 8 + ct) * 2 + 1) * 64 + lane];
      short8 bhf = *(short8*)&bh;
      short8 blf = *(short8*)&bl;
      acc[0][ct] = __builtin_amdgcn_mfma_f32_16x16x32_bf16(af0, bhf, acc[0][ct], 0, 0, 0);
      acc[0][ct] = __builtin_amdgcn_mfma_f32_16x16x32_bf16(af0, blf, acc[0][ct], 0, 0, 0);
      acc[1][ct] = __builtin_amdgcn_mfma_f32_16x16x32_bf16(af1, bhf, acc[1][ct], 0, 0, 0);
      acc[1][ct] = __builtin_amdgcn_mfma_f32_16x16x32_bf16(af1, blf, acc[1][ct], 0, 0, 0);
    }
  }
#pragma unroll
  for (int rf = 0; rf < 2; ++rf) {
#pragma unroll
    for (int ct = 0; ct < 8; ++ct) {
#pragma unroll
      for (int r = 0; r < 4; ++r) {
        float v = acc[rf][ct][r];
        float vo = __shfl_xor(v, 1);
        int row = rowbase + rf * 16 + quad * 4 + r;
        if ((lane & 1) == 0 && row < NN) {
          Bb[row * 64 + ct * 8 + (m >> 1)] = packbf(v, vo);
        }
      }
    }
  }
}

// ---------- aggregation ----------
// Ar[n] = packbf(relu(sum_e w*B[src] + (sum_e w)*base + bias)), BN partial sums,
// and per-graph pooled raw sums (pooling of BN output is affine -> applied in k_z1).
// Each wave owns NPW contiguous nodes => one contiguous CSR edge range (round-1
// measured-best inner loop: single ew buffer, 16 gathers in flight per group).
// At the replication-floor wall: FETCH ~179.7 MB == 8 XCDs x compulsory Bb line
// replication, delivered at the fabric's random-128B-line rate (~2.14 TB/s).
__global__ __launch_bounds__(256) void k_agg(const unsigned* __restrict__ Bb,
                                             const int* __restrict__ rowptr,
                                             const int2* __restrict__ ecw,
                                             const float* __restrict__ bias,
                                             const float* __restrict__ base,
                                             const int* __restrict__ batch,
                                             unsigned* __restrict__ Ar,
                                             float* __restrict__ bnbuf,
                                             float* __restrict__ pooledt) {
  const int lane = threadIdx.x & 63;
  const int wave = threadIdx.x >> 6;
  const int c = lane * 2;
  const int gwave = blockIdx.x * 4 + wave;
  const int n0 = gwave * NPW;
  const float2 bv = *(const float2*)(bias + c);
  const float2 basev = *(const float2*)(base + c);
  float s0 = 0.f, s1 = 0.f, q0 = 0.f, q1 = 0.f;
  __shared__ int srp[4][NPW + 1];
  __shared__ int2 sstage[4][64];
  if (n0 < NN) {
    const int nn = min(NPW, NN - n0);
    if (lane <= nn) srp[wave][lane] = rowptr[n0 + lane];
    int bsp = (lane < nn) ? batch[n0 + lane] : 0;
    float ax0 = 0.f, ax1 = 0.f, ay0 = 0.f, ay1 = 0.f, sw = 0.f;
    float px = 0.f, py = 0.f;
    int gprev = -1;
    auto finalize = [&](int node) {
      float rx = fmaxf(fmaf(sw, basev.x, ax0 + ax1) + bv.x, 0.f);
      float ry = fmaxf(fmaf(sw, basev.y, ay0 + ay1) + bv.y, 0.f);
      Ar[(size_t)(n0 + node) * 64 + lane] = packbf(rx, ry);
      s0 += rx; s1 += ry;
      q0 = fmaf(rx, rx, q0); q1 = fmaf(ry, ry, q1);
      int g = __shfl(bsp, node);
      if (g != gprev) {
        if (gprev >= 0) {
          atomicAdd(&pooledt[(size_t)gprev * 512 + c], px);
          atomicAdd(&pooledt[(size_t)gprev * 512 + c + 1], py);
        }
        gprev = g; px = 0.f; py = 0.f;
      }
      px += rx; py += ry;
      ax0 = 0.f; ax1 = 0.f; ay0 = 0.f; ay1 = 0.f; sw = 0.f;
    };
    const int beg = __builtin_amdgcn_readfirstlane(srp[wave][0]);
    const int endall = __builtin_amdgcn_readfirstlane(srp[wave][nn]);
    int cn = 0;
    // leading (and possibly all) empty nodes
    while (cn < nn && __builtin_amdgcn_readfirstlane(srp[wave][cn + 1]) == beg) {
      finalize(cn);
      ++cn;
    }
    int nend = (cn < nn) ? __builtin_amdgcn_readfirstlane(srp[wave][cn + 1]) : 0x7fffffff;
    int2 stage = (beg + lane < endall) ? ecw[beg + lane] : make_int2(0, 0);
    for (int base_e = beg; base_e < endall; base_e += 64) {
      sstage[wave][lane] = stage;     // current chunk -> LDS (same-wave, in-order)
      const int nb = base_e + 64;
      if (nb < endall) {              // prefetch next chunk off critical path
        stage = (nb + lane < endall) ? ecw[nb + lane] : make_int2(0, 0);
      }
#pragma unroll
      for (int g = 0; g < 4; ++g) {
        if (base_e + g * 16 < endall) {   // wave-uniform (SGPR) branch
          int2 ew[16]; unsigned us[16];
#pragma unroll
          for (int j = 0; j < 16; ++j) ew[j] = sstage[wave][g * 16 + j];  // broadcast
#pragma unroll
          for (int j = 0; j < 16; ++j) {
            const int sj = __builtin_amdgcn_readfirstlane(ew[j].x);       // SGPR base
            us[j] = Bb[((size_t)(unsigned)sj << 6) + (unsigned)lane];
          }
#pragma unroll
          for (int j = 0; j < 16; ++j) {
            const float wj = __int_as_float(ew[j].y);   // 0 for padding lanes
            sw += wj;
            if (j & 1) {
              ax1 = fmaf(wj, bflo(us[j]), ax1);
              ay1 = fmaf(wj, bfhi(us[j]), ay1);
            } else {
              ax0 = fmaf(wj, bflo(us[j]), ax0);
              ay0 = fmaf(wj, bfhi(us[j]), ay0);
            }
            const int e1 = base_e + g * 16 + j + 1;     // scalar
            if (e1 == nend) {                           // node boundary (SGPR cmp)
              finalize(cn);
              ++cn;
              nend = (cn < nn) ? __builtin_amdgcn_readfirstlane(srp[wave][cn + 1]) : 0x7fffffff;
              while (cn < nn && nend == e1) {           // empty nodes inside span
                finalize(cn);
                ++cn;
                nend = (cn < nn) ? __builtin_amdgcn_readfirstlane(srp[wave][cn + 1]) : 0x7fffffff;
              }
            }
          }
        }
      }
    }
    if (gprev >= 0) {
      atomicAdd(&pooledt[(size_t)gprev * 512 + c], px);
      atomicAdd(&pooledt[(size_t)gprev * 512 + c + 1], py);
    }
  }
  __shared__ float sred[4][256];
  sred[wave][c] = s0;
  sred[wave][c + 1] = s1;
  sred[wave][128 + c] = q0;
  sred[wave][128 + c + 1] = q1;
  __syncthreads();
  const int t = threadIdx.x;
  float tot = sred[0][t] + sred[1][t] + sred[2][t] + sred[3][t];
  atomicAdd(&bnbuf[t], tot);
}

// ---------- head ----------

// z1 = (affine-pooled) @ W1 + b1 where pooled_gc = sc_c*S_gc + cnt_g*sh_c
// 4 graphs per block: W1 re-read drops 4x.
__global__ __launch_bounds__(128) void k_z1(const float* __restrict__ S,
                                            const float* __restrict__ bnscL,
                                            const int* __restrict__ gstart,
                                            const float* __restrict__ W1,
                                            const float* __restrict__ b1,
                                            float* __restrict__ z1) {
  __shared__ float sp[4][512];
  const int g0 = blockIdx.x * 4;
  const int c = threadIdx.x;
#pragma unroll
  for (int q = 0; q < 4; ++q) {
    const int g = g0 + q;
    const float cntg = (float)(gstart[g + 1] - gstart[g]);
    for (int i = c; i < 512; i += 128) {
      int tt = i >> 7, ch = i & 127;
      sp[q][i] = fmaf(bnscL[tt * 256 + ch], S[(size_t)g * 512 + i],
                      cntg * bnscL[tt * 256 + 128 + ch]);
    }
  }
  __syncthreads();
  float a0 = b1[c], a1 = a0, a2 = a0, a3 = a0;
  for (int j = 0; j < 512; ++j) {
    float w = W1[j * 128 + c];
    a0 = fmaf(sp[0][j], w, a0);
    a1 = fmaf(sp[1][j], w, a1);
    a2 = fmaf(sp[2][j], w, a2);
    a3 = fmaf(sp[3][j], w, a3);
  }
  z1[(size_t)(g0 + 0) * 128 + c] = a0;
  z1[(size_t)(g0 + 1) * 128 + c] = a1;
  z1[(size_t)(g0 + 2) * 128 + c] = a2;
  z1[(size_t)(g0 + 3) * 128 + c] = a3;
}

// 1024 threads: 8 g-strided partial passes (coalesced in c) + LDS reduce
__global__ __launch_bounds__(1024) void k_zstat(const float* __restrict__ z1,
                                                const float* __restrict__ g1,
                                                const float* __restrict__ bt1,
                                                float* __restrict__ zsc) {
  const int t = threadIdx.x;
  const int c = t & 127;
  const int gr = t >> 7;   // 0..7
  float s = 0.f, q = 0.f;
  for (int g = gr; g < GG; g += 8) {
    float v = z1[(size_t)g * 128 + c];
    s += v;
    q = fmaf(v, v, q);
  }
  __shared__ float ss[8][128];
  __shared__ float sq[8][128];
  ss[gr][c] = s;
  sq[gr][c] = q;
  __syncthreads();
  if (t < 128) {
    float st = 0.f, qt = 0.f;
#pragma unroll
    for (int i = 0; i < 8; ++i) { st += ss[i][c]; qt += sq[i][c]; }
    float mu = st * (1.0f / GG);
    float var = qt * (1.0f / GG) - mu * mu;
    float inv = rsqrtf(var + EPSF);
    float sc = g1[c] * inv;
    zsc[c] = sc;
    zsc[128 + c] = bt1[c] - mu * sc;
  }
}

__global__ __launch_bounds__(128) void k_out(const float* __restrict__ z1,
                                             const float* __restrict__ zsc,
                                             const float* __restrict__ W2,
                                             const float* __restrict__ b2,
                                             float* __restrict__ out) {
  __shared__ float zr[128];
  const int g = blockIdx.x;
  const int c = threadIdx.x;
  zr[c] = fmaxf(fmaf(z1[(size_t)g * 128 + c], zsc[c], zsc[128 + c]), 0.f);
  __syncthreads();
  if (c < OUTC) {
    float acc = b2[c];
    for (int k = 0; k < 128; ++k) acc = fmaf(zr[k], W2[k * OUTC + c], acc);
    out[(size_t)g * OUTC + c] = acc;
  }
}

// ---------- launch ----------

extern "C" void kernel_launch(void* const* d_in, const int* in_sizes, int n_in,
                              void* d_out, int out_size, void* d_ws, size_t ws_size,
                              hipStream_t stream) {
  const float* x      = (const float*)d_in[0];
  const int*   ei     = (const int*)d_in[1];
  const int*   batch  = (const int*)d_in[2];
  const float* Ws     = (const float*)d_in[3];
  const float* bs     = (const float*)d_in[4];
  const float* gammas = (const float*)d_in[5];
  const float* betas  = (const float*)d_in[6];
  const float* W1     = (const float*)d_in[7];
  const float* b1     = (const float*)d_in[8];
  const float* g1     = (const float*)d_in[9];
  const float* bt1    = (const float*)d_in[10];
  const float* W2     = (const float*)d_in[11];
  const float* b2     = (const float*)d_in[12];
  float* out = (float*)d_out;

  char* ws = (char*)d_ws;
  size_t off = 0;
  auto alloc = [&](size_t bytes) -> void* {
    void* p = ws + off;
    off = (off + bytes + 255) & ~(size_t)255;
    return p;
  };
  // zero-initialized region (single memset)
  int*   deg    = (int*)alloc((size_t)NN * 4);
  int*   cnt    = (int*)alloc((size_t)NN * 4);
  float* bnbuf  = (float*)alloc((size_t)LL * 256 * 4);
  float* pooled = (float*)alloc((size_t)GG * 512 * 4);
  float* zbase  = (float*)alloc(128 * 4);          // zeros: layer-0 base term
  size_t zero_bytes = off;
  // rest
  unsigned* Ar     = (unsigned*)alloc((size_t)NN * 64 * 4); // packed bf16 relu output
  unsigned* Ab     = (unsigned*)alloc((size_t)NN * 64 * 4); // packed bf16 layer-0 GEMM input
  unsigned* Bb     = (unsigned*)alloc((size_t)NN * 64 * 4); // packed bf16 H@W (gather src)
  int2*     ecw    = (int2*)alloc((size_t)EE * 8);
  float*    dinv   = (float*)alloc((size_t)NN * 4);
  int*      rowptr = (int*)alloc((size_t)(NN + 1) * 4);
  int*      bsum   = (int*)alloc((size_t)NSCB * 4);
  int*      gstart = (int*)alloc((size_t)(GG + 1) * 4);
  uint4*    Wf     = (uint4*)alloc((size_t)4096 * 16);      // MFMA W fragments (hi/lo), one layer
  float*    z1     = (float*)alloc((size_t)GG * FF * 4);
  float*    bnscL  = (float*)alloc((size_t)LL * 256 * 4);   // per-layer BN (sc, sh)
  float*    basebf = (float*)alloc(128 * 4);                // sh @ W_{t+1}
  float*    zsc    = (float*)alloc(256 * 4);
  (void)ws_size; (void)in_sizes; (void)n_in; (void)out_size;

  hipMemsetAsync(d_ws, 0, zero_bytes, stream);

  k_deg<<<(EE + 255) / 256, 256, 0, stream>>>(ei + EE, deg);
  k_bsum<<<NSCB, 256, 0, stream>>>(deg, bsum, dinv);
  k_rowptr<<<NSCB, 256, 0, stream>>>(deg, bsum, rowptr);
  k_fill<<<(EE + 255) / 256, 256, 0, stream>>>(ei, rowptr, cnt, dinv, ecw);
  k_cvt<<<(NN * 64 + 255) / 256, 256, 0, stream>>>(x, batch, Ab, gstart);
  k_wcvt<<<16, 256, 0, stream>>>(Ws, Wf);

  for (int t = 0; t < LL; ++t) {
    k_mm<<<(NN + 127) / 128, 256, 0, stream>>>(t == 0 ? Ab : Ar, Wf, Bb);
    k_agg<<<AGG_BLOCKS, 256, 0, stream>>>(Bb, rowptr, ecw, bs + t * FF,
                                          t == 0 ? zbase : basebf, batch,
                                          Ar, bnbuf + t * 256, pooled + t * FF);
    if (t < LL - 1) {
      k_post<<<17, 256, 0, stream>>>(bnbuf + t * 256, gammas + t * FF, betas + t * FF,
                                     bnscL + t * 256, Ws + (size_t)(t + 1) * 16384,
                                     Wf, basebf);
    } else {
      k_post<<<1, 256, 0, stream>>>(bnbuf + t * 256, gammas + t * FF, betas + t * FF,
                                    bnscL + t * 256, nullptr, nullptr, nullptr);
    }
  }

  k_z1<<<GG / 4, 128, 0, stream>>>(pooled, bnscL, gstart, W1, b1, z1);
  k_zstat<<<1, 1024, 0, stream>>>(z1, g1, bt1, zsc);
  k_out<<<GG, 128, 0, stream>>>(z1, zsc, W2, b2, out);
}

// Round 7
// 799.157 us; speedup vs baseline: 1.7365x; 1.0197x over previous
//
#include <hip/hip_runtime.h>

#define NN 100000
#define EE 1600000
#define FF 128
#define LL 4
#define GG 512
#define OUTC 10
#define EPSF 1e-5f
#define NSCB ((NN + 255) / 256)   // 391 scan blocks

// k_agg geometry: each wave owns NPW contiguous nodes => contiguous CSR edge range
#define NPW 16
#define AGG_WAVES ((NN + NPW - 1) / NPW)
#define AGG_BLOCKS ((AGG_WAVES + 3) / 4)

typedef __attribute__((ext_vector_type(8))) short short8;
typedef __attribute__((ext_vector_type(4))) float f32x4;

__device__ inline unsigned bf16rne(float f) {
  unsigned u = __float_as_uint(f);
  return (u + 0x7fffu + ((u >> 16) & 1u)) >> 16;
}
__device__ inline unsigned packbf(float lo, float hi) {
  return bf16rne(lo) | (bf16rne(hi) << 16);
}
__device__ inline float bflo(unsigned u) { return __uint_as_float(u << 16); }
__device__ inline float bfhi(unsigned u) { return __uint_as_float(u & 0xffff0000u); }

// ---------- graph setup ----------

__global__ __launch_bounds__(256) void k_deg(const int* __restrict__ col, int* __restrict__ deg) {
  int e = blockIdx.x * 256 + threadIdx.x;
  if (e < EE) atomicAdd(&deg[col[e]], 1);
}

// per-block degree sums (391 blocks x 256) + dinv (fused elementwise)
__global__ __launch_bounds__(256) void k_bsum(const int* __restrict__ deg,
                                              int* __restrict__ bsum,
                                              float* __restrict__ dinv) {
  int i = blockIdx.x * 256 + threadIdx.x;
  int v = (i < NN) ? deg[i] : 0;
  if (i < NN) dinv[i] = v > 0 ? rsqrtf((float)v) : 0.0f;
#pragma unroll
  for (int off = 32; off > 0; off >>= 1) v += __shfl_down(v, off, 64);
  __shared__ int ws[4];
  if ((threadIdx.x & 63) == 0) ws[threadIdx.x >> 6] = v;
  __syncthreads();
  if (threadIdx.x == 0) bsum[blockIdx.x] = ws[0] + ws[1] + ws[2] + ws[3];
}

// each block: scan all block sums in LDS (redundant), local scan of its 256 degs,
// write exclusive rowptr. rowptr[NN] = EE (constant).
__global__ __launch_bounds__(256) void k_rowptr(const int* __restrict__ deg,
                                                const int* __restrict__ bsum,
                                                int* __restrict__ rowptr) {
  __shared__ int sb[512];
  __shared__ int sd[256];
  const int t = threadIdx.x;
  sb[t]       = (t < NSCB) ? bsum[t] : 0;
  sb[t + 256] = (t + 256 < NSCB) ? bsum[t + 256] : 0;
  __syncthreads();
#pragma unroll
  for (int off = 1; off < 512; off <<= 1) {
    int v0 = (t >= off) ? sb[t - off] : 0;
    int v1 = sb[t + 256 - off];
    __syncthreads();
    sb[t] += v0;
    sb[t + 256] += v1;
    __syncthreads();
  }
  const int bpre = (blockIdx.x == 0) ? 0 : sb[blockIdx.x - 1];
  const int i = blockIdx.x * 256 + t;
  const int d = (i < NN) ? deg[i] : 0;
  sd[t] = d;
  __syncthreads();
#pragma unroll
  for (int off = 1; off < 256; off <<= 1) {
    int v = (t >= off) ? sd[t - off] : 0;
    __syncthreads();
    sd[t] += v;
    __syncthreads();
  }
  if (i < NN) rowptr[i] = bpre + sd[t] - d;
  if (blockIdx.x == 0 && t == 0) rowptr[NN] = EE;
}

// build CSR: one interleaved (src, weight) int2 store per edge.
// Countdown slot allocation reuses deg (dead after k_rowptr): no cnt array.
// Within-node edge order is irrelevant (weighted sum).
__global__ __launch_bounds__(256) void k_fill(const int* __restrict__ ei,
                                              const int* __restrict__ rowptr,
                                              int* __restrict__ deg,
                                              const float* __restrict__ dinv,
                                              int2* __restrict__ ecw) {
  int e = blockIdx.x * 256 + threadIdx.x;
  if (e >= EE) return;
  int r = ei[e];
  int cl = ei[EE + e];
  int slot = rowptr[cl] + (atomicSub(&deg[cl], 1) - 1);
  ecw[slot] = make_int2(r, __float_as_int(dinv[r] * dinv[cl]));
}

// ---------- bf16 conversions ----------

// x[N,128] fp32 -> Ab packed bf16 pairs; fused: gstart bounds from sorted batch
__global__ __launch_bounds__(256) void k_cvt(const float* __restrict__ x,
                                             const int* __restrict__ batch,
                                             unsigned* __restrict__ Ab,
                                             int* __restrict__ gstart) {
  int i = blockIdx.x * 256 + threadIdx.x;
  if (i < NN * 64) {
    float2 v = *(const float2*)(x + (size_t)i * 2);
    Ab[i] = packbf(v.x, v.y);
  }
  if (i < NN) {
    int b = batch[i];
    if (i == 0) {
      for (int g = 0; g <= b; ++g) gstart[g] = 0;
    } else {
      int bp = batch[i - 1];
      for (int g = bp + 1; g <= b; ++g) gstart[g] = i;
    }
    if (i == NN - 1) {
      for (int g = b + 1; g <= GG; ++g) gstart[g] = NN;
    }
  }
}

// W[128,128] fp32 -> MFMA B-fragments, hi/lo bf16 split (layer-0, no scale).
// frag index: ((kc*8 + ct)*2 + which), 64 lanes * 16B.
__global__ __launch_bounds__(256) void k_wcvt(const float* __restrict__ W,
                                              uint4* __restrict__ Wf) {
  int tid = blockIdx.x * 256 + threadIdx.x;   // 0..4095
  int lane = tid & 63;
  int which = (tid >> 6) & 1;
  int ct = (tid >> 7) & 7;
  int kc = tid >> 10;
  int n = ct * 16 + (lane & 15);
  int k0 = kc * 32 + (lane >> 4) * 8;
  unsigned h[8];
#pragma unroll
  for (int j = 0; j < 8; ++j) {
    float w = W[(k0 + j) * 128 + n];
    unsigned hb = bf16rne(w);
    if (which == 0) {
      h[j] = hb;
    } else {
      float hf = __uint_as_float(hb << 16);
      h[j] = bf16rne(w - hf);
    }
  }
  uint4 o;
  o.x = h[0] | (h[1] << 16);
  o.y = h[2] | (h[3] << 16);
  o.z = h[4] | (h[5] << 16);
  o.w = h[6] | (h[7] << 16);
  Wf[tid] = o;
}

// Fused per-layer epilogue (separate dispatch — fusing this into k_agg via
// threadfence+ticket cost 2.6x on k_agg, round 5): every block computes BN
// affine (sc, sh) from bnbuf (redundant, 512 B); block 0 stores it to bnsc.
// If gridDim>1 (not last layer): blocks 0..15 emit next layer's scaled W
// fragments, block 16 computes base[c] = sum_k sh[k]*Wnext[k,c].
__global__ __launch_bounds__(256) void k_post(const float* __restrict__ bnbuf,
                                              const float* __restrict__ gamma,
                                              const float* __restrict__ beta,
                                              float* __restrict__ bnsc,
                                              const float* __restrict__ Wnext,
                                              uint4* __restrict__ Wf,
                                              float* __restrict__ baseo) {
  __shared__ float ssc[256];
  const int t = threadIdx.x;
  if (t < 128) {
    float mu = bnbuf[t] * (1.0f / NN);
    float var = bnbuf[128 + t] * (1.0f / NN) - mu * mu;
    float inv = rsqrtf(var + EPSF);
    float sc = gamma[t] * inv;
    float sh = beta[t] - mu * sc;
    ssc[t] = sc;
    ssc[128 + t] = sh;
    if (blockIdx.x == 0) {
      bnsc[t] = sc;
      bnsc[128 + t] = sh;
    }
  }
  __syncthreads();
  if (gridDim.x == 1) return;   // last layer: stats only
  if (blockIdx.x < 16) {
    int tid = blockIdx.x * 256 + t;
    int lane = tid & 63;
    int which = (tid >> 6) & 1;
    int ct = (tid >> 7) & 7;
    int kc = tid >> 10;
    int n = ct * 16 + (lane & 15);
    int k0 = kc * 32 + (lane >> 4) * 8;
    unsigned h[8];
#pragma unroll
    for (int j = 0; j < 8; ++j) {
      float w = Wnext[(k0 + j) * 128 + n] * ssc[k0 + j];
      unsigned hb = bf16rne(w);
      if (which == 0) {
        h[j] = hb;
      } else {
        float hf = __uint_as_float(hb << 16);
        h[j] = bf16rne(w - hf);
      }
    }
    uint4 o;
    o.x = h[0] | (h[1] << 16);
    o.y = h[2] | (h[3] << 16);
    o.z = h[4] | (h[5] << 16);
    o.w = h[6] | (h[7] << 16);
    Wf[tid] = o;
  } else if (t < 128) {
    float acc = 0.f;
    for (int k = 0; k < 128; ++k) acc = fmaf(ssc[128 + k], Wnext[k * 128 + t], acc);
    baseo[t] = acc;
  }
}

// ---------- per-layer GEMM via MFMA: Bb[N,128](packed bf16) = Ab @ (Whi+Wlo) ----------
// Measured-best form: 16 rows/wave, 64 rows/block (32-row variant regressed the
// non-agg total by ~24 us in round 6 — higher acc VGPR cost outweighed Wf reuse).
__global__ __launch_bounds__(256) void k_mm(const unsigned* __restrict__ Ab,
                                            const uint4* __restrict__ Wf,
                                            unsigned* __restrict__ Bb) {
  const int lane = threadIdx.x & 63;
  const int w = threadIdx.x >> 6;
  const int quad = lane >> 4;
  const int m = lane & 15;
  const int rowbase = blockIdx.x * 64 + w * 16;
  const int arow = min(rowbase + m, NN - 1);
  const uint4* A4 = (const uint4*)Ab;
  f32x4 acc[8];
#pragma unroll
  for (int ct = 0; ct < 8; ++ct) acc[ct] = (f32x4){0.f, 0.f, 0.f, 0.f};
#pragma unroll
  for (int kc = 0; kc < 4; ++kc) {
    uint4 av = A4[arow * 16 + kc * 4 + quad];
    short8 af = *(short8*)&av;
#pragma unroll
    for (int ct = 0; ct < 8; ++ct) {
      uint4 bh = Wf[((kc * 8 + ct) * 2 + 0) * 64 + lane];
      uint4 bl = Wf[((kc * 8 + ct) * 2 + 1) * 64 + lane];
      acc[ct] = __builtin_amdgcn_mfma_f32_16x16x32_bf16(af, *(short8*)&bh, acc[ct], 0, 0, 0);
      acc[ct] = __builtin_amdgcn_mfma_f32_16x16x32_bf16(af, *(short8*)&bl, acc[ct], 0, 0, 0);
    }
  }
#pragma unroll
  for (int ct = 0; ct < 8; ++ct) {
#pragma unroll
    for (int r = 0; r < 4; ++r) {
      float v = acc[ct][r];
      float vo = __shfl_xor(v, 1);
      int row = rowbase + quad * 4 + r;
      if ((lane & 1) == 0 && row < NN) {
        Bb[row * 64 + ct * 8 + (m >> 1)] = packbf(v, vo);
      }
    }
  }
}

// ---------- aggregation ----------
// Ar[n] = packbf(relu(sum_e w*B[src] + (sum_e w)*base + bias)), BN partial sums,
// and per-graph pooled raw sums (pooling of BN output is affine -> applied in k_z1).
// Each wave owns NPW contiguous nodes => one contiguous CSR edge range (round-1
// measured-best inner loop: single ew buffer, 16 gathers in flight per group).
// At the replication-floor wall: FETCH ~179.7 MB == 8 XCDs x compulsory Bb line
// replication, delivered at the fabric's random-128B-line rate (~2.14 TB/s).
__global__ __launch_bounds__(256) void k_agg(const unsigned* __restrict__ Bb,
                                             const int* __restrict__ rowptr,
                                             const int2* __restrict__ ecw,
                                             const float* __restrict__ bias,
                                             const float* __restrict__ base,
                                             const int* __restrict__ batch,
                                             unsigned* __restrict__ Ar,
                                             float* __restrict__ bnbuf,
                                             float* __restrict__ pooledt) {
  const int lane = threadIdx.x & 63;
  const int wave = threadIdx.x >> 6;
  const int c = lane * 2;
  const int gwave = blockIdx.x * 4 + wave;
  const int n0 = gwave * NPW;
  const float2 bv = *(const float2*)(bias + c);
  const float2 basev = *(const float2*)(base + c);
  float s0 = 0.f, s1 = 0.f, q0 = 0.f, q1 = 0.f;
  __shared__ int srp[4][NPW + 1];
  __shared__ int2 sstage[4][64];
  if (n0 < NN) {
    const int nn = min(NPW, NN - n0);
    if (lane <= nn) srp[wave][lane] = rowptr[n0 + lane];
    int bsp = (lane < nn) ? batch[n0 + lane] : 0;
    float ax0 = 0.f, ax1 = 0.f, ay0 = 0.f, ay1 = 0.f, sw = 0.f;
    float px = 0.f, py = 0.f;
    int gprev = -1;
    auto finalize = [&](int node) {
      float rx = fmaxf(fmaf(sw, basev.x, ax0 + ax1) + bv.x, 0.f);
      float ry = fmaxf(fmaf(sw, basev.y, ay0 + ay1) + bv.y, 0.f);
      Ar[(size_t)(n0 + node) * 64 + lane] = packbf(rx, ry);
      s0 += rx; s1 += ry;
      q0 = fmaf(rx, rx, q0); q1 = fmaf(ry, ry, q1);
      int g = __shfl(bsp, node);
      if (g != gprev) {
        if (gprev >= 0) {
          atomicAdd(&pooledt[(size_t)gprev * 512 + c], px);
          atomicAdd(&pooledt[(size_t)gprev * 512 + c + 1], py);
        }
        gprev = g; px = 0.f; py = 0.f;
      }
      px += rx; py += ry;
      ax0 = 0.f; ax1 = 0.f; ay0 = 0.f; ay1 = 0.f; sw = 0.f;
    };
    const int beg = __builtin_amdgcn_readfirstlane(srp[wave][0]);
    const int endall = __builtin_amdgcn_readfirstlane(srp[wave][nn]);
    int cn = 0;
    // leading (and possibly all) empty nodes
    while (cn < nn && __builtin_amdgcn_readfirstlane(srp[wave][cn + 1]) == beg) {
      finalize(cn);
      ++cn;
    }
    int nend = (cn < nn) ? __builtin_amdgcn_readfirstlane(srp[wave][cn + 1]) : 0x7fffffff;
    int2 stage = (beg + lane < endall) ? ecw[beg + lane] : make_int2(0, 0);
    for (int base_e = beg; base_e < endall; base_e += 64) {
      sstage[wave][lane] = stage;     // current chunk -> LDS (same-wave, in-order)
      const int nb = base_e + 64;
      if (nb < endall) {              // prefetch next chunk off critical path
        stage = (nb + lane < endall) ? ecw[nb + lane] : make_int2(0, 0);
      }
#pragma unroll
      for (int g = 0; g < 4; ++g) {
        if (base_e + g * 16 < endall) {   // wave-uniform (SGPR) branch
          int2 ew[16]; unsigned us[16];
#pragma unroll
          for (int j = 0; j < 16; ++j) ew[j] = sstage[wave][g * 16 + j];  // broadcast
#pragma unroll
          for (int j = 0; j < 16; ++j) {
            const int sj = __builtin_amdgcn_readfirstlane(ew[j].x);       // SGPR base
            us[j] = Bb[((size_t)(unsigned)sj << 6) + (unsigned)lane];
          }
#pragma unroll
          for (int j = 0; j < 16; ++j) {
            const float wj = __int_as_float(ew[j].y);   // 0 for padding lanes
            sw += wj;
            if (j & 1) {
              ax1 = fmaf(wj, bflo(us[j]), ax1);
              ay1 = fmaf(wj, bfhi(us[j]), ay1);
            } else {
              ax0 = fmaf(wj, bflo(us[j]), ax0);
              ay0 = fmaf(wj, bfhi(us[j]), ay0);
            }
            const int e1 = base_e + g * 16 + j + 1;     // scalar
            if (e1 == nend) {                           // node boundary (SGPR cmp)
              finalize(cn);
              ++cn;
              nend = (cn < nn) ? __builtin_amdgcn_readfirstlane(srp[wave][cn + 1]) : 0x7fffffff;
              while (cn < nn && nend == e1) {           // empty nodes inside span
                finalize(cn);
                ++cn;
                nend = (cn < nn) ? __builtin_amdgcn_readfirstlane(srp[wave][cn + 1]) : 0x7fffffff;
              }
            }
          }
        }
      }
    }
    if (gprev >= 0) {
      atomicAdd(&pooledt[(size_t)gprev * 512 + c], px);
      atomicAdd(&pooledt[(size_t)gprev * 512 + c + 1], py);
    }
  }
  __shared__ float sred[4][256];
  sred[wave][c] = s0;
  sred[wave][c + 1] = s1;
  sred[wave][128 + c] = q0;
  sred[wave][128 + c + 1] = q1;
  __syncthreads();
  const int t = threadIdx.x;
  float tot = sred[0][t] + sred[1][t] + sred[2][t] + sred[3][t];
  atomicAdd(&bnbuf[t], tot);
}

// ---------- head ----------

// z1 = (affine-pooled) @ W1 + b1 where pooled_gc = sc_c*S_gc + cnt_g*sh_c
// 4 graphs per block: W1 re-read drops 4x.
__global__ __launch_bounds__(128) void k_z1(const float* __restrict__ S,
                                            const float* __restrict__ bnscL,
                                            const int* __restrict__ gstart,
                                            const float* __restrict__ W1,
                                            const float* __restrict__ b1,
                                            float* __restrict__ z1) {
  __shared__ float sp[4][512];
  const int g0 = blockIdx.x * 4;
  const int c = threadIdx.x;
#pragma unroll
  for (int q = 0; q < 4; ++q) {
    const int g = g0 + q;
    const float cntg = (float)(gstart[g + 1] - gstart[g]);
    for (int i = c; i < 512; i += 128) {
      int tt = i >> 7, ch = i & 127;
      sp[q][i] = fmaf(bnscL[tt * 256 + ch], S[(size_t)g * 512 + i],
                      cntg * bnscL[tt * 256 + 128 + ch]);
    }
  }
  __syncthreads();
  float a0 = b1[c], a1 = a0, a2 = a0, a3 = a0;
  for (int j = 0; j < 512; ++j) {
    float w = W1[j * 128 + c];
    a0 = fmaf(sp[0][j], w, a0);
    a1 = fmaf(sp[1][j], w, a1);
    a2 = fmaf(sp[2][j], w, a2);
    a3 = fmaf(sp[3][j], w, a3);
  }
  z1[(size_t)(g0 + 0) * 128 + c] = a0;
  z1[(size_t)(g0 + 1) * 128 + c] = a1;
  z1[(size_t)(g0 + 2) * 128 + c] = a2;
  z1[(size_t)(g0 + 3) * 128 + c] = a3;
}

// 1024 threads: 8 g-strided partial passes (coalesced in c) + LDS reduce
__global__ __launch_bounds__(1024) void k_zstat(const float* __restrict__ z1,
                                                const float* __restrict__ g1,
                                                const float* __restrict__ bt1,
                                                float* __restrict__ zsc) {
  const int t = threadIdx.x;
  const int c = t & 127;
  const int gr = t >> 7;   // 0..7
  float s = 0.f, q = 0.f;
  for (int g = gr; g < GG; g += 8) {
    float v = z1[(size_t)g * 128 + c];
    s += v;
    q = fmaf(v, v, q);
  }
  __shared__ float ss[8][128];
  __shared__ float sq[8][128];
  ss[gr][c] = s;
  sq[gr][c] = q;
  __syncthreads();
  if (t < 128) {
    float st = 0.f, qt = 0.f;
#pragma unroll
    for (int i = 0; i < 8; ++i) { st += ss[i][c]; qt += sq[i][c]; }
    float mu = st * (1.0f / GG);
    float var = qt * (1.0f / GG) - mu * mu;
    float inv = rsqrtf(var + EPSF);
    float sc = g1[c] * inv;
    zsc[c] = sc;
    zsc[128 + c] = bt1[c] - mu * sc;
  }
}

__global__ __launch_bounds__(128) void k_out(const float* __restrict__ z1,
                                             const float* __restrict__ zsc,
                                             const float* __restrict__ W2,
                                             const float* __restrict__ b2,
                                             float* __restrict__ out) {
  __shared__ float zr[128];
  const int g = blockIdx.x;
  const int c = threadIdx.x;
  zr[c] = fmaxf(fmaf(z1[(size_t)g * 128 + c], zsc[c], zsc[128 + c]), 0.f);
  __syncthreads();
  if (c < OUTC) {
    float acc = b2[c];
    for (int k = 0; k < 128; ++k) acc = fmaf(zr[k], W2[k * OUTC + c], acc);
    out[(size_t)g * OUTC + c] = acc;
  }
}

// ---------- launch ----------

extern "C" void kernel_launch(void* const* d_in, const int* in_sizes, int n_in,
                              void* d_out, int out_size, void* d_ws, size_t ws_size,
                              hipStream_t stream) {
  const float* x      = (const float*)d_in[0];
  const int*   ei     = (const int*)d_in[1];
  const int*   batch  = (const int*)d_in[2];
  const float* Ws     = (const float*)d_in[3];
  const float* bs     = (const float*)d_in[4];
  const float* gammas = (const float*)d_in[5];
  const float* betas  = (const float*)d_in[6];
  const float* W1     = (const float*)d_in[7];
  const float* b1     = (const float*)d_in[8];
  const float* g1     = (const float*)d_in[9];
  const float* bt1    = (const float*)d_in[10];
  const float* W2     = (const float*)d_in[11];
  const float* b2     = (const float*)d_in[12];
  float* out = (float*)d_out;

  char* ws = (char*)d_ws;
  size_t off = 0;
  auto alloc = [&](size_t bytes) -> void* {
    void* p = ws + off;
    off = (off + bytes + 255) & ~(size_t)255;
    return p;
  };
  // zero-initialized region (single memset)
  int*   deg    = (int*)alloc((size_t)NN * 4);
  float* bnbuf  = (float*)alloc((size_t)LL * 256 * 4);
  float* pooled = (float*)alloc((size_t)GG * 512 * 4);
  float* zbase  = (float*)alloc(128 * 4);          // zeros: layer-0 base term
  size_t zero_bytes = off;
  // rest
  unsigned* Ar     = (unsigned*)alloc((size_t)NN * 64 * 4); // packed bf16 relu output
  unsigned* Ab     = (unsigned*)alloc((size_t)NN * 64 * 4); // packed bf16 layer-0 GEMM input
  unsigned* Bb     = (unsigned*)alloc((size_t)NN * 64 * 4); // packed bf16 H@W (gather src)
  int2*     ecw    = (int2*)alloc((size_t)EE * 8);
  float*    dinv   = (float*)alloc((size_t)NN * 4);
  int*      rowptr = (int*)alloc((size_t)(NN + 1) * 4);
  int*      bsum   = (int*)alloc((size_t)NSCB * 4);
  int*      gstart = (int*)alloc((size_t)(GG + 1) * 4);
  uint4*    Wf     = (uint4*)alloc((size_t)4096 * 16);      // MFMA W fragments (hi/lo), one layer
  float*    z1     = (float*)alloc((size_t)GG * FF * 4);
  float*    bnscL  = (float*)alloc((size_t)LL * 256 * 4);   // per-layer BN (sc, sh)
  float*    basebf = (float*)alloc(128 * 4);                // sh @ W_{t+1}
  float*    zsc    = (float*)alloc(256 * 4);
  (void)ws_size; (void)in_sizes; (void)n_in; (void)out_size;

  hipMemsetAsync(d_ws, 0, zero_bytes, stream);

  k_deg<<<(EE + 255) / 256, 256, 0, stream>>>(ei + EE, deg);
  k_bsum<<<NSCB, 256, 0, stream>>>(deg, bsum, dinv);
  k_rowptr<<<NSCB, 256, 0, stream>>>(deg, bsum, rowptr);
  k_fill<<<(EE + 255) / 256, 256, 0, stream>>>(ei, rowptr, deg, dinv, ecw);
  k_cvt<<<(NN * 64 + 255) / 256, 256, 0, stream>>>(x, batch, Ab, gstart);
  k_wcvt<<<16, 256, 0, stream>>>(Ws, Wf);

  for (int t = 0; t < LL; ++t) {
    k_mm<<<(NN + 63) / 64, 256, 0, stream>>>(t == 0 ? Ab : Ar, Wf, Bb);
    k_agg<<<AGG_BLOCKS, 256, 0, stream>>>(Bb, rowptr, ecw, bs + t * FF,
                                          t == 0 ? zbase : basebf, batch,
                                          Ar, bnbuf + t * 256, pooled + t * FF);
    if (t < LL - 1) {
      k_post<<<17, 256, 0, stream>>>(bnbuf + t * 256, gammas + t * FF, betas + t * FF,
                                     bnscL + t * 256, Ws + (size_t)(t + 1) * 16384,
                                     Wf, basebf);
    } else {
      k_post<<<1, 256, 0, stream>>>(bnbuf + t * 256, gammas + t * FF, betas + t * FF,
                                    bnscL + t * 256, nullptr, nullptr, nullptr);
    }
  }

  k_z1<<<GG / 4, 128, 0, stream>>>(pooled, bnscL, gstart, W1, b1, z1);
  k_zstat<<<1, 1024, 0, stream>>>(z1, g1, bt1, zsc);
  k_out<<<GG, 128, 0, stream>>>(z1, zsc, W2, b2, out);
}